// Round 1
// baseline (548.392 us; speedup 1.0000x reference)
//
#include <hip/hip_runtime.h>
#include <stdint.h>

#define Bn 16
#define C 64
#define H 256
#define W 256
#define HW (H * W)          // 65536
#define NHW (Bn * HW)       // 1048576

// ---------------------------------------------------------------------------
// Kernel 1: weight prep. One wave (64 threads) per output channel o.
// wbits[o*9 + tap] bit c = (w[o][c][tap] > 0); scale[o] = mean |w| over 576.
// ---------------------------------------------------------------------------
__global__ void prep_weights(const float* __restrict__ w,
                             uint64_t* __restrict__ wbits,
                             float* __restrict__ scale) {
    int o = blockIdx.x;     // 64 blocks
    int c = threadIdx.x;    // 64 threads = 1 wave
    const float* wp = w + ((size_t)o * C + c) * 9;
    float asum = 0.f;
#pragma unroll
    for (int tap = 0; tap < 9; ++tap) {
        float v = wp[tap];
        asum += fabsf(v);
        uint64_t m = __ballot(v > 0.f);   // bit c = sign bit of channel c
        if (c == 0) wbits[o * 9 + tap] = m;
    }
#pragma unroll
    for (int off = 32; off > 0; off >>= 1)
        asum += __shfl_down(asum, off);
    if (c == 0) scale[o] = asum * (1.f / 576.f);
}

// ---------------------------------------------------------------------------
// Kernel 2: pack z = sign(x + bias) into 64-bit words, one word per pixel.
// Thread p -> pixel (n, h, w); loops over 64 channels (coalesced per c-iter).
// ---------------------------------------------------------------------------
__global__ __launch_bounds__(256) void pack_z(const float* __restrict__ x,
                                              const float* __restrict__ bias,
                                              uint64_t* __restrict__ zbits) {
    int p = blockIdx.x * 256 + threadIdx.x;   // grid exactly covers NHW
    int n = p >> 16;                          // / HW
    int hw = p & (HW - 1);
    const float* xp = x + (size_t)n * C * HW + hw;
    uint64_t bits = 0;
#pragma unroll
    for (int c = 0; c < C; ++c) {
        float v = xp[(size_t)c * HW] + bias[c];
        bits |= (uint64_t)(v > 0.f) << c;
    }
    zbits[p] = bits;
}

// ---------------------------------------------------------------------------
// Kernel 3: binary conv + RPReLU + residual. Thread = one pixel, all 64 o.
// dot[o] = 64*nvalid - 2 * sum_{valid taps} popc(wbits[o][tap] ^ zb[tap])
// y = scale[o]*dot + pb0[o]; prelu; + pb1[o]; + x (identity)
// ---------------------------------------------------------------------------
__global__ __launch_bounds__(256) void bconv(const uint64_t* __restrict__ zbits,
                                             const uint64_t* __restrict__ wbits,
                                             const float* __restrict__ scale,
                                             const float* __restrict__ x,
                                             const float* __restrict__ pb0,
                                             const float* __restrict__ aw,
                                             const float* __restrict__ pb1,
                                             float* __restrict__ out) {
    __shared__ uint64_t swb[576];
    __shared__ float sscale[C], spb0[C], sa[C], spb1[C];
    int t = threadIdx.x;
    if (t < C) {
        sscale[t] = scale[t];
        spb0[t]   = pb0[t];
        sa[t]     = aw[t];
        spb1[t]   = pb1[t];
    }
    for (int i = t; i < 576; i += 256) swb[i] = wbits[i];
    __syncthreads();

    int p = blockIdx.x * 256 + t;
    int n = p >> 16;
    int hw = p & (HW - 1);
    int h = hw >> 8;      // W = 256
    int w = hw & (W - 1);

    const uint64_t* zrow = zbits + (size_t)n * HW;
    uint64_t zb[9];
    int vmask[9];
    int nvalid = 0;
#pragma unroll
    for (int dh = -1; dh <= 1; ++dh) {
#pragma unroll
        for (int dw = -1; dw <= 1; ++dw) {
            int tap = (dh + 1) * 3 + (dw + 1);
            int hh = h + dh, ww = w + dw;
            bool valid = ((unsigned)hh < (unsigned)H) && ((unsigned)ww < (unsigned)W);
            vmask[tap] = valid ? -1 : 0;
            nvalid += valid ? 1 : 0;
            zb[tap] = valid ? zrow[hh * W + ww] : 0ull;
        }
    }

    const float* xid = x + (size_t)n * C * HW + hw;
    float* op = out + (size_t)n * C * HW + hw;
    int base = 64 * nvalid;

#pragma unroll 4
    for (int o = 0; o < C; ++o) {
        const uint64_t* wp = &swb[o * 9];
        int s = 0;
#pragma unroll
        for (int tap = 0; tap < 9; ++tap)
            s += vmask[tap] & (int)__popcll(wp[tap] ^ zb[tap]);
        float y = sscale[o] * (float)(base - 2 * s) + spb0[o];
        y = y > 0.f ? y : sa[o] * y;
        y += spb1[o];
        op[(size_t)o * HW] = y + xid[(size_t)o * HW];
    }
}

// ---------------------------------------------------------------------------
extern "C" void kernel_launch(void* const* d_in, const int* in_sizes, int n_in,
                              void* d_out, int out_size, void* d_ws, size_t ws_size,
                              hipStream_t stream) {
    const float* x           = (const float*)d_in[0];
    const float* move0_bias  = (const float*)d_in[1];
    const float* conv_weight = (const float*)d_in[2];
    const float* prelu_w     = (const float*)d_in[3];
    const float* pr_bias0    = (const float*)d_in[4];
    const float* pr_bias1    = (const float*)d_in[5];
    float* out = (float*)d_out;

    uint8_t* ws = (uint8_t*)d_ws;
    uint64_t* zbits = (uint64_t*)ws;                                  // 8 MB
    uint64_t* wbits = (uint64_t*)(ws + (size_t)NHW * 8);              // 4608 B
    float* scale    = (float*)(ws + (size_t)NHW * 8 + 576 * 8);       // 256 B

    prep_weights<<<64, 64, 0, stream>>>(conv_weight, wbits, scale);
    pack_z<<<NHW / 256, 256, 0, stream>>>(x, move0_bias, zbits);
    bconv<<<NHW / 256, 256, 0, stream>>>(zbits, wbits, scale, x,
                                         pr_bias0, prelu_w, pr_bias1, out);
}